// Round 13
// baseline (507.133 us; speedup 1.0000x reference)
//
#include <hip/hip_runtime.h>
#include <hip/hip_bf16.h>
#include <math.h>

// Problem constants (structure of the model; N/E derived at runtime)
#define NPG   100
#define FIN   128
#define KK    30
#define NC    10
#define FC    97    // concat feature width: 32+32+32+1
#define XCS   100   // padded row stride for the concat buffer (16B-aligned rows)

#define BKT_SHIFT 6          // 64 nodes per bucket
#define BKT_N     64
#define NBMAX     2048       // supports N up to 131072 (also the src-packing limit 2^17)
#define CHA       4096       // edges per block in sort pass A
#define NBLKMAX   1024       // supports E up to 1024*4096 = 4.19M
#define BCAP      2560       // LDS-cached edges per bucket in pass B (mean 2048, +11 sigma)

__device__ inline void fma4(float4& a, float s, const float4& w) {
    a.x += s * w.x; a.y += s * w.y; a.z += s * w.z; a.w += s * w.w;
}
__device__ inline void scl4(float4& a, float s) { a.x *= s; a.y *= s; a.z *= s; a.w *= s; }
__device__ inline void add4(float4& a, const float4& b) { a.x += b.x; a.y += b.y; a.z += b.z; a.w += b.w; }

// ---------------- CSR build: transpose bucket sort (NO contended global atomics) ----

__global__ void sortA(const int* __restrict__ src, const int* __restrict__ dst,
                      int* __restrict__ ebuf, int* __restrict__ cntmat,
                      int E, int NB) {
    __shared__ int hist[NBMAX];                 // counts -> cursors
    __shared__ __align__(16) int seg[CHA];
    __shared__ int ps[256];
    int t = threadIdx.x, k = blockIdx.x;
    int e0 = k * CHA;
    int len = E - e0; if (len > CHA) len = CHA;
    int len4 = len >> 2;
    const int4* dst4 = (const int4*)(dst + e0);
    const int4* src4 = (const int4*)(src + e0);
    for (int i = t; i < NB; i += 256) hist[i] = 0;
    __syncthreads();
    for (int i = t; i < len4; i += 256) {
        int4 d = dst4[i];
        atomicAdd(&hist[d.x >> BKT_SHIFT], 1);
        atomicAdd(&hist[d.y >> BKT_SHIFT], 1);
        atomicAdd(&hist[d.z >> BKT_SHIFT], 1);
        atomicAdd(&hist[d.w >> BKT_SHIFT], 1);
    }
    for (int i = (len4 << 2) + t; i < len; i += 256)
        atomicAdd(&hist[dst[e0 + i] >> BKT_SHIFT], 1);
    __syncthreads();
    int chunk = (NB + 255) >> 8;
    int lo = t * chunk; if (lo > NB) lo = NB;
    int hi = lo + chunk; if (hi > NB) hi = NB;
    int s = 0;
    for (int i = lo; i < hi; ++i) s += hist[i];
    ps[t] = s;
    __syncthreads();
    for (int d = 1; d < 256; d <<= 1) {
        int v = (t >= d) ? ps[t - d] : 0;
        __syncthreads();
        ps[t] += v;
        __syncthreads();
    }
    int base = (t == 0) ? 0 : ps[t - 1];
    for (int i = lo; i < hi; ++i) {
        int c = hist[i];
        cntmat[(size_t)k * NB + i] = base | (c << 16);
        hist[i] = base;
        base += c;
    }
    __syncthreads();
    for (int i = t; i < len4; i += 256) {
        int4 d = dst4[i];
        int4 sv = src4[i];
        int r0 = atomicAdd(&hist[d.x >> BKT_SHIFT], 1); seg[r0] = sv.x | ((d.x & (BKT_N - 1)) << 17);
        int r1 = atomicAdd(&hist[d.y >> BKT_SHIFT], 1); seg[r1] = sv.y | ((d.y & (BKT_N - 1)) << 17);
        int r2 = atomicAdd(&hist[d.z >> BKT_SHIFT], 1); seg[r2] = sv.z | ((d.z & (BKT_N - 1)) << 17);
        int r3 = atomicAdd(&hist[d.w >> BKT_SHIFT], 1); seg[r3] = sv.w | ((d.w & (BKT_N - 1)) << 17);
    }
    for (int i = (len4 << 2) + t; i < len; i += 256) {
        int e = e0 + i;
        int d = dst[e];
        int r = atomicAdd(&hist[d >> BKT_SHIFT], 1);
        seg[r] = src[e] | ((d & (BKT_N - 1)) << 17);
    }
    __syncthreads();
    int4* eb4 = (int4*)(ebuf + e0);
    for (int i = t; i < len4; i += 256) eb4[i] = ((const int4*)seg)[i];
    for (int i = (len4 << 2) + t; i < len; i += 256) ebuf[e0 + i] = seg[i];
}

// tiled transpose cntmat[k][b] -> cntmatT[b][k], fused per-tile column sums -> colsum
#define TT 32
__global__ void transp(const int* __restrict__ A, int* __restrict__ B,
                       int* __restrict__ colsum, int R, int C) {
    __shared__ int tile[TT][TT + 1];
    int c0 = blockIdx.x * TT, r0 = blockIdx.y * TT;
    int tx = threadIdx.x & 31, ty = threadIdx.x >> 5;
    for (int dy = ty; dy < TT; dy += 8) {
        int r = r0 + dy, c = c0 + tx;
        tile[dy][tx] = (r < R && c < C) ? A[(size_t)r * C + c] : 0;
    }
    __syncthreads();
    for (int dy = ty; dy < TT; dy += 8) {
        int c = c0 + dy, r = r0 + tx;
        if (c < C && r < R) B[(size_t)c * R + r] = tile[tx][dy];
    }
    if (ty == 0 && c0 + tx < C) {
        int s = 0;
#pragma unroll
        for (int dy = 0; dy < TT; ++dy) s += (tile[dy][tx] >> 16) & 0xFFFF;
        if (s) atomicAdd(&colsum[c0 + tx], s);
    }
}

__global__ void scan_nb(const int* __restrict__ colsum, int* __restrict__ boff,
                        int* __restrict__ off, int NB, int N, int E) {
    __shared__ int ps[256];
    int t = threadIdx.x;
    int chunk = (NB + 255) >> 8;
    int lo = t * chunk; if (lo > NB) lo = NB;
    int hi = lo + chunk; if (hi > NB) hi = NB;
    int s = 0;
    for (int i = lo; i < hi; ++i) s += colsum[i];
    ps[t] = s;
    __syncthreads();
    for (int d = 1; d < 256; d <<= 1) {
        int v = (t >= d) ? ps[t - d] : 0;
        __syncthreads();
        ps[t] += v;
        __syncthreads();
    }
    int base = (t == 0) ? 0 : ps[t - 1];
    for (int i = lo; i < hi; ++i) { boff[i] = base; base += colsum[i]; }
    if (t == 255) { boff[NB] = E; off[N] = E; }
}

__global__ void bucketB(const int* __restrict__ ebuf, const int* __restrict__ cntmatT,
                        const int* __restrict__ boff,
                        int* __restrict__ eby, int* __restrict__ off,
                        float* __restrict__ dinv, int N, int NB, int NBLK) {
    __shared__ int cc[NBLKMAX];      // after rescan: base | scanned_offset<<16
    __shared__ int ps[256];
    __shared__ int seg[BCAP];
    __shared__ int lcnt[BKT_N];
    __shared__ int lcur[BKT_N];
    int b = blockIdx.x, t = threadIdx.x;
    int n0 = b << BKT_SHIFT;
    int s = boff[b];
    int len = boff[b + 1] - s;
    for (int k = t; k < NBLK; k += 256) cc[k] = cntmatT[(size_t)b * NBLK + k];
    if (t < BKT_N) lcnt[t] = 0;
    __syncthreads();
    int chunk = (NBLK + 255) >> 8;
    int lo = t * chunk; if (lo > NBLK) lo = NBLK;
    int hi = lo + chunk; if (hi > NBLK) hi = NBLK;
    int sm = 0;
    for (int i = lo; i < hi; ++i) sm += (cc[i] >> 16) & 0xFFFF;
    ps[t] = sm;
    __syncthreads();
    for (int d = 1; d < 256; d <<= 1) {
        int v = (t >= d) ? ps[t - d] : 0;
        __syncthreads();
        ps[t] += v;
        __syncthreads();
    }
    int base = (t == 0) ? 0 : ps[t - 1];
    for (int i = lo; i < hi; ++i) {
        int c = (cc[i] >> 16) & 0xFFFF;
        cc[i] = (cc[i] & 0xFFFF) | (base << 16);
        base += c;
    }
    __syncthreads();
    bool fits = (len <= BCAP);
    for (int i = t; i < len; i += 256) {
        int l = 0, h = NBLK;
        while (h - l > 1) { int m = (l + h) >> 1; if ((cc[m] >> 16) <= i) l = m; else h = m; }
        int v = ebuf[l * CHA + (cc[l] & 0xFFFF) + (i - (cc[l] >> 16))];
        if (fits) seg[i] = v;
        atomicAdd(&lcnt[v >> 17], 1);
    }
    __syncthreads();
    if (t == 0) {
        int run = s;
        for (int i = 0; i < BKT_N; ++i) { lcur[i] = run; run += lcnt[i]; }
    }
    __syncthreads();
    if (t < BKT_N) {
        int n = n0 + t;
        if (n < N) { off[n] = lcur[t]; dinv[n] = rsqrtf((float)lcnt[t] + 1.0f); }
    }
    __syncthreads();
    if (fits) {
        for (int i = t; i < len; i += 256) {
            int v = seg[i];
            int pos = atomicAdd(&lcur[v >> 17], 1);
            eby[pos] = v & 0x1FFFF;
        }
    } else {
        for (int i = t; i < len; i += 256) {
            int l = 0, h = NBLK;
            while (h - l > 1) { int m = (l + h) >> 1; if ((cc[m] >> 16) <= i) l = m; else h = m; }
            int v = ebuf[l * CHA + (cc[l] & 0xFFFF) + (i - (cc[l] >> 16))];
            int pos = atomicAdd(&lcur[v >> 17], 1);
            eby[pos] = v & 0x1FFFF;
        }
    }
}

// ---------------- GEMMs (write slice-major hS[4][N][8], pre-scaled by dinv) --------

__device__ inline float* hS_ptr(float* hS, int sliceStride, int n, int cg) {
    return hS + (size_t)(cg >> 3) * sliceStride + (size_t)n * 8 + (cg & 7);
}

__global__ void gemm128_32s(const float* __restrict__ x, const float* __restrict__ W,
                            const float* __restrict__ dinv, float* __restrict__ hS,
                            int N, int sliceStride) {
    __shared__ float Ws[128 * 32];
    int t = threadIdx.x;
    for (int i = t; i < 128 * 32; i += 256) Ws[i] = W[i];
    __syncthreads();
    int cg = (t & 7) * 4;
    int n0 = blockIdx.x * 128 + (t >> 3) * 4;
    if (n0 >= N) return;
    if (n0 + 4 <= N) {
        const float* xr = x + (size_t)n0 * 128;
        float4 a0 = {0,0,0,0}, a1 = a0, a2 = a0, a3 = a0;
#pragma unroll
        for (int k4 = 0; k4 < 32; ++k4) {
            float4 x0 = *(const float4*)(xr + k4 * 4);
            float4 x1 = *(const float4*)(xr + 128 + k4 * 4);
            float4 x2 = *(const float4*)(xr + 256 + k4 * 4);
            float4 x3 = *(const float4*)(xr + 384 + k4 * 4);
            float4 w0 = *(const float4*)&Ws[(4 * k4 + 0) * 32 + cg];
            float4 w1 = *(const float4*)&Ws[(4 * k4 + 1) * 32 + cg];
            float4 w2 = *(const float4*)&Ws[(4 * k4 + 2) * 32 + cg];
            float4 w3 = *(const float4*)&Ws[(4 * k4 + 3) * 32 + cg];
            fma4(a0, x0.x, w0); fma4(a0, x0.y, w1); fma4(a0, x0.z, w2); fma4(a0, x0.w, w3);
            fma4(a1, x1.x, w0); fma4(a1, x1.y, w1); fma4(a1, x1.z, w2); fma4(a1, x1.w, w3);
            fma4(a2, x2.x, w0); fma4(a2, x2.y, w1); fma4(a2, x2.z, w2); fma4(a2, x2.w, w3);
            fma4(a3, x3.x, w0); fma4(a3, x3.y, w1); fma4(a3, x3.z, w2); fma4(a3, x3.w, w3);
        }
        scl4(a0, dinv[n0]); scl4(a1, dinv[n0 + 1]); scl4(a2, dinv[n0 + 2]); scl4(a3, dinv[n0 + 3]);
        *(float4*)hS_ptr(hS, sliceStride, n0 + 0, cg) = a0;
        *(float4*)hS_ptr(hS, sliceStride, n0 + 1, cg) = a1;
        *(float4*)hS_ptr(hS, sliceStride, n0 + 2, cg) = a2;
        *(float4*)hS_ptr(hS, sliceStride, n0 + 3, cg) = a3;
    } else {
        for (int nn = 0; nn < 4; ++nn) {
            int n = n0 + nn; if (n >= N) break;
            float4 a = {0,0,0,0};
            for (int k = 0; k < 128; ++k)
                fma4(a, x[(size_t)n * 128 + k], *(const float4*)&Ws[k * 32 + cg]);
            scl4(a, dinv[n]);
            *(float4*)hS_ptr(hS, sliceStride, n, cg) = a;
        }
    }
}

__global__ void gemm32_32s(const float* __restrict__ xc, int colOff,
                           const float* __restrict__ W, const float* __restrict__ dinv,
                           float* __restrict__ hS, int N, int sliceStride) {
    __shared__ float Ws[32 * 32];
    int t = threadIdx.x;
    for (int i = t; i < 32 * 32; i += 256) Ws[i] = W[i];
    __syncthreads();
    int cg = (t & 7) * 4;
    int n0 = blockIdx.x * 128 + (t >> 3) * 4;
    if (n0 >= N) return;
    if (n0 + 4 <= N) {
        const float* xr = xc + (size_t)n0 * XCS + colOff;
        float4 a0 = {0,0,0,0}, a1 = a0, a2 = a0, a3 = a0;
#pragma unroll
        for (int k4 = 0; k4 < 8; ++k4) {
            float4 x0 = *(const float4*)(xr + k4 * 4);
            float4 x1 = *(const float4*)(xr + XCS + k4 * 4);
            float4 x2 = *(const float4*)(xr + 2 * XCS + k4 * 4);
            float4 x3 = *(const float4*)(xr + 3 * XCS + k4 * 4);
            float4 w0 = *(const float4*)&Ws[(4 * k4 + 0) * 32 + cg];
            float4 w1 = *(const float4*)&Ws[(4 * k4 + 1) * 32 + cg];
            float4 w2 = *(const float4*)&Ws[(4 * k4 + 2) * 32 + cg];
            float4 w3 = *(const float4*)&Ws[(4 * k4 + 3) * 32 + cg];
            fma4(a0, x0.x, w0); fma4(a0, x0.y, w1); fma4(a0, x0.z, w2); fma4(a0, x0.w, w3);
            fma4(a1, x1.x, w0); fma4(a1, x1.y, w1); fma4(a1, x1.z, w2); fma4(a1, x1.w, w3);
            fma4(a2, x2.x, w0); fma4(a2, x2.y, w1); fma4(a2, x2.z, w2); fma4(a2, x2.w, w3);
            fma4(a3, x3.x, w0); fma4(a3, x3.y, w1); fma4(a3, x3.z, w2); fma4(a3, x3.w, w3);
        }
        scl4(a0, dinv[n0]); scl4(a1, dinv[n0 + 1]); scl4(a2, dinv[n0 + 2]); scl4(a3, dinv[n0 + 3]);
        *(float4*)hS_ptr(hS, sliceStride, n0 + 0, cg) = a0;
        *(float4*)hS_ptr(hS, sliceStride, n0 + 1, cg) = a1;
        *(float4*)hS_ptr(hS, sliceStride, n0 + 2, cg) = a2;
        *(float4*)hS_ptr(hS, sliceStride, n0 + 3, cg) = a3;
    } else {
        for (int nn = 0; nn < 4; ++nn) {
            int n = n0 + nn; if (n >= N) break;
            float4 a = {0,0,0,0};
            for (int k = 0; k < 32; ++k)
                fma4(a, xc[(size_t)n * XCS + colOff + k], *(const float4*)&Ws[k * 32 + cg]);
            scl4(a, dinv[n]);
            *(float4*)hS_ptr(hS, sliceStride, n, cg) = a;
        }
    }
}

// hv'[N] = (xc[:, colOff:colOff+32] @ W4[32]) * dinv[n]
__global__ void gemm32_1(const float* __restrict__ xc, int colOff,
                         const float* __restrict__ W4, const float* __restrict__ dinv,
                         float* __restrict__ hv, int N) {
    __shared__ float W4s[32];
    int t = threadIdx.x;
    if (t < 32) W4s[t] = W4[t];
    __syncthreads();
    int n = blockIdx.x * 256 + t;
    if (n >= N) return;
    const float* xr = xc + (size_t)n * XCS + colOff;
    float a = 0.f;
#pragma unroll
    for (int k4 = 0; k4 < 8; ++k4) {
        float4 xv = *(const float4*)(xr + k4 * 4);
        a += xv.x * W4s[4 * k4] + xv.y * W4s[4 * k4 + 1]
           + xv.z * W4s[4 * k4 + 2] + xv.w * W4s[4 * k4 + 3];
    }
    hv[n] = a * dinv[n];
}

// ---------------- aggregation: XCD-pinned channel slices ----------------
// Slice s (8 channels, 3.2MB) is processed only by blocks with (blockIdx&3)==s,
// which land on XCDs s and s+4 (blockIdx%8 -> XCD round-robin). Each XCD's L2
// then holds ONE slice for the whole pass: gathers become L2 hits.
// h pre-scaled by dinv: out = tanh(dn * (h'[n] + sum h'[s]) + b)

__global__ void agg32s(const float* __restrict__ hS, const int* __restrict__ off,
                       const int* __restrict__ eby, const float* __restrict__ dinv,
                       const float* __restrict__ b, float* __restrict__ xc, int colOff,
                       int N, int sliceStride, int nchunks) {
    int bidx = blockIdx.x;
    int xl = bidx & 7;
    int slice = xl & 3, pair = xl >> 2;
    int chunk = (bidx >> 3) * 2 + pair;
    if (chunk >= nchunks) return;
    int t = threadIdx.x;
    int n = chunk * 128 + (t >> 1);
    int half = t & 1;
    if (n >= N) return;
    const float4* h4 = (const float4*)(hS + (size_t)slice * sliceStride);
    float dn = dinv[n];
    float4 acc = h4[(size_t)n * 2 + half];
    float4 c1 = {0,0,0,0}, c2 = {0,0,0,0}, c3 = {0,0,0,0};
    int e0 = off[n], e1 = off[n + 1];
    int j = e0;
    for (; j + 3 < e1; j += 4) {
        int s0 = eby[j], s1 = eby[j + 1], s2 = eby[j + 2], s3 = eby[j + 3];
        float4 g0 = h4[(size_t)s0 * 2 + half];
        float4 g1 = h4[(size_t)s1 * 2 + half];
        float4 g2 = h4[(size_t)s2 * 2 + half];
        float4 g3 = h4[(size_t)s3 * 2 + half];
        add4(acc, g0); add4(c1, g1); add4(c2, g2); add4(c3, g3);
    }
    for (; j < e1; ++j) add4(acc, h4[(size_t)eby[j] * 2 + half]);
    add4(c1, c2); add4(acc, c3); add4(acc, c1);
    float4 bb = *(const float4*)&b[slice * 8 + half * 4];
    float4 o;
    o.x = tanhf(acc.x * dn + bb.x);
    o.y = tanhf(acc.y * dn + bb.y);
    o.z = tanhf(acc.z * dn + bb.z);
    o.w = tanhf(acc.w * dn + bb.w);
    *(float4*)&xc[(size_t)n * XCS + colOff + slice * 8 + half * 4] = o;
}

__global__ void agg1(const float* __restrict__ hv, const int* __restrict__ off,
                     const int* __restrict__ eby, const float* __restrict__ dinv,
                     const float* __restrict__ b4, float* __restrict__ xc, int N) {
    int n = blockIdx.x * 256 + threadIdx.x;
    if (n >= N) return;
    float dn = dinv[n];
    float acc = hv[n], c1 = 0.f, c2 = 0.f, c3 = 0.f;
    int e0 = off[n], e1 = off[n + 1];
    int j = e0;
    for (; j + 3 < e1; j += 4) {
        acc += hv[eby[j]]; c1 += hv[eby[j + 1]]; c2 += hv[eby[j + 2]]; c3 += hv[eby[j + 3]];
    }
    for (; j < e1; ++j) acc += hv[eby[j]];
    xc[(size_t)n * XCS + 96] = tanhf((acc + c1 + c2 + c3) * dn + b4[0]);
}

// ---------------- fused head ----------------

__global__ void head_kernel(const float* __restrict__ xc,
                            const float* __restrict__ c5w, const float* __restrict__ c5b,
                            const float* __restrict__ c6w, const float* __restrict__ c6b,
                            const float* __restrict__ f1w, const float* __restrict__ f1b,
                            const float* __restrict__ f2w, const float* __restrict__ f2b,
                            float* __restrict__ out) {
    __shared__ float v[NPG];
    __shared__ int   ord[KK];
    __shared__ float topk[KK * FC];
    __shared__ float o5[16 * 30];
    __shared__ float p5[16 * 15];
    __shared__ float z[352];
    __shared__ float h1[128];
    __shared__ float lg[NC];
    __shared__ float lse;

    int g = blockIdx.x;
    int t = threadIdx.x;
    const float* xg = xc + (size_t)g * NPG * XCS;

    if (t < NPG) v[t] = xg[t * XCS + 96];
    __syncthreads();
    if (t < NPG) {
        float vi = v[t];
        int r = 0;
        for (int j = 0; j < NPG; ++j) {
            float vj = v[j];
            r += (vj > vi) || (vj == vi && j < t);  // stable descending rank
        }
        if (r < KK) ord[r] = t;
    }
    __syncthreads();
    for (int i = t; i < KK * FC; i += 128) {
        int r = i / FC, f = i - r * FC;
        topk[i] = xg[ord[r] * XCS + f];
    }
    __syncthreads();
    for (int i = t; i < 16 * 30; i += 128) {
        int ch = i / 30, tt = i - ch * 30;
        float a = c5b[ch];
        const float* w = c5w + ch * FC;
        const float* xx = topk + tt * FC;
        for (int f = 0; f < FC; ++f) a += xx[f] * w[f];
        o5[ch * 30 + tt] = fmaxf(a, 0.f);
    }
    __syncthreads();
    for (int i = t; i < 16 * 15; i += 128) {
        int ch = i / 15, tt = i - ch * 15;
        p5[i] = fmaxf(o5[ch * 30 + 2 * tt], o5[ch * 30 + 2 * tt + 1]);
    }
    __syncthreads();
    for (int i = t; i < 32 * 11; i += 128) {
        int oc = i / 11, tt = i - oc * 11;
        float a = c6b[oc];
#pragma unroll
        for (int ic = 0; ic < 16; ++ic) {
#pragma unroll
            for (int k = 0; k < 5; ++k)
                a += p5[ic * 15 + tt + k] * c6w[oc * 80 + ic * 5 + k];
        }
        z[oc * 11 + tt] = fmaxf(a, 0.f);
    }
    __syncthreads();
    {
        float a = f1b[t];
        for (int i = 0; i < 352; ++i) a += z[i] * f1w[i * 128 + t];
        h1[t] = fmaxf(a, 0.f);
    }
    __syncthreads();
    if (t < NC) {
        float a = f2b[t];
#pragma unroll
        for (int j = 0; j < 128; ++j) a += h1[j] * f2w[j * NC + t];
        lg[t] = a;
    }
    __syncthreads();
    if (t == 0) {
        float m = lg[0];
        for (int c = 1; c < NC; ++c) m = fmaxf(m, lg[c]);
        float s = 0.f;
        for (int c = 0; c < NC; ++c) s += expf(lg[c] - m);
        lse = m + logf(s);
    }
    __syncthreads();
    if (t < NC) out[(size_t)g * NC + t] = lg[t] - lse;
}

// ---------------- launch ----------------

static inline size_t align_up(size_t x, size_t a) { return (x + a - 1) & ~(a - 1); }

extern "C" void kernel_launch(void* const* d_in, const int* in_sizes, int n_in,
                              void* d_out, int out_size, void* d_ws, size_t ws_size,
                              hipStream_t stream) {
    const float* x   = (const float*)d_in[0];
    const int*   ei  = (const int*)d_in[1];
    const float* W1  = (const float*)d_in[3];
    const float* b1  = (const float*)d_in[4];
    const float* W2  = (const float*)d_in[5];
    const float* b2  = (const float*)d_in[6];
    const float* W3  = (const float*)d_in[7];
    const float* b3  = (const float*)d_in[8];
    const float* W4  = (const float*)d_in[9];
    const float* b4  = (const float*)d_in[10];
    const float* c5w = (const float*)d_in[11];
    const float* c5b = (const float*)d_in[12];
    const float* c6w = (const float*)d_in[13];
    const float* c6b = (const float*)d_in[14];
    const float* f1w = (const float*)d_in[15];
    const float* f1b = (const float*)d_in[16];
    const float* f2w = (const float*)d_in[17];
    const float* f2b = (const float*)d_in[18];
    float* out = (float*)d_out;

    const int N = in_sizes[0] / FIN;
    const int E = in_sizes[1] / 2;
    const int G = N / NPG;
    const int NB = (N + BKT_N - 1) >> BKT_SHIFT;  // buckets of 64 nodes
    const int NBLK = (E + CHA - 1) / CHA;         // sort blocks
    const int sliceStride = N * 8;                // floats per 8-channel slice
    const int* src = ei;
    const int* dst = ei + E;

    // workspace plan (with lifetime unions):
    //  [colsum][boff][dinv][off][hv][ ebuf | hS ][ eby | cntmat ][ xcb | cntmatT ]
    char* ws = (char*)d_ws;
    size_t o = 0;
    int*   colsum = (int*)(ws + o); o = align_up(o + (size_t)NB * 4, 256);
    int*   boff   = (int*)(ws + o); o = align_up(o + (size_t)(NB + 1) * 4, 256);
    float* dinv   = (float*)(ws + o); o = align_up(o + (size_t)N * 4, 256);
    int*   off    = (int*)(ws + o); o = align_up(o + (size_t)(N + 1) * 4, 256);
    float* hv     = (float*)(ws + o); o = align_up(o + (size_t)N * 4, 256);
    size_t big = (size_t)(E > N * 32 ? E : N * 32);
    int*   ebuf   = (int*)(ws + o); float* hS = (float*)(ws + o);
    o = align_up(o + big * 4, 256);
    size_t big2 = (size_t)E * 4 > (size_t)NBLK * NB * 4 ? (size_t)E * 4 : (size_t)NBLK * NB * 4;
    int*   eby    = (int*)(ws + o); int* cntmat = (int*)(ws + o);
    o = align_up(o + big2, 256);
    size_t big3 = (size_t)N * XCS * 4 > (size_t)NBLK * NB * 4 ? (size_t)N * XCS * 4 : (size_t)NBLK * NB * 4;
    float* xcb    = (float*)(ws + o); int* cntmatT = (int*)(ws + o);
    o = align_up(o + big3, 256);
    (void)ws_size;

    hipMemsetAsync(colsum, 0, (size_t)NB * 4, stream);

    int gbN  = (N + 255) / 256;
    int gbN128 = (N + 127) / 128;
    int nchunks = (N + 127) / 128;
    int gridA = 8 * ((nchunks + 1) / 2);

    sortA<<<NBLK, 256, 0, stream>>>(src, dst, ebuf, cntmat, E, NB);
    dim3 tg((NB + TT - 1) / TT, (NBLK + TT - 1) / TT);
    transp<<<tg, 256, 0, stream>>>(cntmat, cntmatT, colsum, NBLK, NB);
    scan_nb<<<1, 256, 0, stream>>>(colsum, boff, off, NB, N, E);
    bucketB<<<NB, 256, 0, stream>>>(ebuf, cntmatT, boff, eby, off, dinv, N, NB, NBLK);

    // layer 1: x @ W1 -> hS (slice-major, pre-scaled)
    gemm128_32s<<<gbN128, 256, 0, stream>>>(x, W1, dinv, hS, N, sliceStride);
    agg32s<<<gridA, 256, 0, stream>>>(hS, off, eby, dinv, b1, xcb, 0, N, sliceStride, nchunks);
    // layer 2
    gemm32_32s<<<gbN128, 256, 0, stream>>>(xcb, 0, W2, dinv, hS, N, sliceStride);
    agg32s<<<gridA, 256, 0, stream>>>(hS, off, eby, dinv, b2, xcb, 32, N, sliceStride, nchunks);
    // layer 3
    gemm32_32s<<<gbN128, 256, 0, stream>>>(xcb, 32, W3, dinv, hS, N, sliceStride);
    agg32s<<<gridA, 256, 0, stream>>>(hS, off, eby, dinv, b3, xcb, 64, N, sliceStride, nchunks);
    // layer 4
    gemm32_1<<<gbN, 256, 0, stream>>>(xcb, 64, W4, dinv, hv, N);
    agg1<<<gbN, 256, 0, stream>>>(hv, off, eby, dinv, b4, xcb, N);

    // head
    head_kernel<<<G, 128, 0, stream>>>(xcb, c5w, c5b, c6w, c6b, f1w, f1b, f2w, f2b, out);
}

// Round 14
// 305.884 us; speedup vs baseline: 1.6579x; 1.6579x over previous
//
#include <hip/hip_runtime.h>
#include <hip/hip_bf16.h>
#include <math.h>

// Problem constants (structure of the model; N/E derived at runtime)
#define NPG   100
#define FIN   128
#define KK    30
#define NC    10
#define FC    97    // concat feature width: 32+32+32+1
#define XCS   100   // padded row stride for the concat buffer (16B-aligned rows)

#define BKT_SHIFT 6          // 64 nodes per bucket
#define BKT_N     64
#define NBMAX     2048       // supports N up to 131072 (also the src-packing limit 2^17)
#define CHA       4096       // edges per block in sort pass A
#define NBLKMAX   1024       // supports E up to 1024*4096 = 4.19M
#define BCAP      2560       // LDS-cached edges per bucket in pass B (mean 2048, +11 sigma)

__device__ inline void fma4(float4& a, float s, const float4& w) {
    a.x += s * w.x; a.y += s * w.y; a.z += s * w.z; a.w += s * w.w;
}
__device__ inline void scl4(float4& a, float s) { a.x *= s; a.y *= s; a.z *= s; a.w *= s; }
__device__ inline void add4(float4& a, const float4& b) { a.x += b.x; a.y += b.y; a.z += b.z; a.w += b.w; }

// ---------------- CSR build: transpose bucket sort (NO contended global atomics) ----

__global__ void sortA(const int* __restrict__ src, const int* __restrict__ dst,
                      int* __restrict__ ebuf, int* __restrict__ cntmat,
                      int E, int NB) {
    __shared__ int hist[NBMAX];                 // counts -> cursors
    __shared__ __align__(16) int seg[CHA];
    __shared__ int ps[256];
    int t = threadIdx.x, k = blockIdx.x;
    int e0 = k * CHA;
    int len = E - e0; if (len > CHA) len = CHA;
    int len4 = len >> 2;
    const int4* dst4 = (const int4*)(dst + e0);
    const int4* src4 = (const int4*)(src + e0);
    for (int i = t; i < NB; i += 256) hist[i] = 0;
    __syncthreads();
    for (int i = t; i < len4; i += 256) {
        int4 d = dst4[i];
        atomicAdd(&hist[d.x >> BKT_SHIFT], 1);
        atomicAdd(&hist[d.y >> BKT_SHIFT], 1);
        atomicAdd(&hist[d.z >> BKT_SHIFT], 1);
        atomicAdd(&hist[d.w >> BKT_SHIFT], 1);
    }
    for (int i = (len4 << 2) + t; i < len; i += 256)
        atomicAdd(&hist[dst[e0 + i] >> BKT_SHIFT], 1);
    __syncthreads();
    int chunk = (NB + 255) >> 8;
    int lo = t * chunk; if (lo > NB) lo = NB;
    int hi = lo + chunk; if (hi > NB) hi = NB;
    int s = 0;
    for (int i = lo; i < hi; ++i) s += hist[i];
    ps[t] = s;
    __syncthreads();
    for (int d = 1; d < 256; d <<= 1) {
        int v = (t >= d) ? ps[t - d] : 0;
        __syncthreads();
        ps[t] += v;
        __syncthreads();
    }
    int base = (t == 0) ? 0 : ps[t - 1];
    for (int i = lo; i < hi; ++i) {
        int c = hist[i];
        cntmat[(size_t)k * NB + i] = base | (c << 16);
        hist[i] = base;
        base += c;
    }
    __syncthreads();
    for (int i = t; i < len4; i += 256) {
        int4 d = dst4[i];
        int4 sv = src4[i];
        int r0 = atomicAdd(&hist[d.x >> BKT_SHIFT], 1); seg[r0] = sv.x | ((d.x & (BKT_N - 1)) << 17);
        int r1 = atomicAdd(&hist[d.y >> BKT_SHIFT], 1); seg[r1] = sv.y | ((d.y & (BKT_N - 1)) << 17);
        int r2 = atomicAdd(&hist[d.z >> BKT_SHIFT], 1); seg[r2] = sv.z | ((d.z & (BKT_N - 1)) << 17);
        int r3 = atomicAdd(&hist[d.w >> BKT_SHIFT], 1); seg[r3] = sv.w | ((d.w & (BKT_N - 1)) << 17);
    }
    for (int i = (len4 << 2) + t; i < len; i += 256) {
        int e = e0 + i;
        int d = dst[e];
        int r = atomicAdd(&hist[d >> BKT_SHIFT], 1);
        seg[r] = src[e] | ((d & (BKT_N - 1)) << 17);
    }
    __syncthreads();
    int4* eb4 = (int4*)(ebuf + e0);
    for (int i = t; i < len4; i += 256) eb4[i] = ((const int4*)seg)[i];
    for (int i = (len4 << 2) + t; i < len; i += 256) ebuf[e0 + i] = seg[i];
}

#define TT 32
__global__ void transp(const int* __restrict__ A, int* __restrict__ B, int R, int C) {
    __shared__ int tile[TT][TT + 1];
    int c0 = blockIdx.x * TT, r0 = blockIdx.y * TT;
    int tx = threadIdx.x & 31, ty = threadIdx.x >> 5;
    for (int dy = ty; dy < TT; dy += 8) {
        int r = r0 + dy, c = c0 + tx;
        tile[dy][tx] = (r < R && c < C) ? A[(size_t)r * C + c] : 0;
    }
    __syncthreads();
    for (int dy = ty; dy < TT; dy += 8) {
        int c = c0 + dy, r = r0 + tx;
        if (c < C && r < R) B[(size_t)c * R + r] = tile[tx][dy];
    }
}

__global__ void colsum_k(const int* __restrict__ cntmatT, int* __restrict__ colsum,
                         int NBLK) {
    __shared__ int red[256];
    int b = blockIdx.x, t = threadIdx.x;
    const int* row = cntmatT + (size_t)b * NBLK;
    int s = 0;
    for (int k = t; k < NBLK; k += 256) s += (row[k] >> 16) & 0xFFFF;
    red[t] = s;
    __syncthreads();
    for (int d = 128; d > 0; d >>= 1) {
        if (t < d) red[t] += red[t + d];
        __syncthreads();
    }
    if (t == 0) colsum[b] = red[0];
}

__global__ void scan_nb(const int* __restrict__ colsum, int* __restrict__ boff,
                        int* __restrict__ off, int NB, int N, int E) {
    __shared__ int ps[256];
    int t = threadIdx.x;
    int chunk = (NB + 255) >> 8;
    int lo = t * chunk; if (lo > NB) lo = NB;
    int hi = lo + chunk; if (hi > NB) hi = NB;
    int s = 0;
    for (int i = lo; i < hi; ++i) s += colsum[i];
    ps[t] = s;
    __syncthreads();
    for (int d = 1; d < 256; d <<= 1) {
        int v = (t >= d) ? ps[t - d] : 0;
        __syncthreads();
        ps[t] += v;
        __syncthreads();
    }
    int base = (t == 0) ? 0 : ps[t - 1];
    for (int i = lo; i < hi; ++i) { boff[i] = base; base += colsum[i]; }
    if (t == 255) { boff[NB] = E; off[N] = E; }
}

__global__ void bucketB(const int* __restrict__ ebuf, const int* __restrict__ cntmatT,
                        const int* __restrict__ boff,
                        int* __restrict__ eby, int* __restrict__ off,
                        float* __restrict__ dinv, int N, int NB, int NBLK) {
    __shared__ int cc[NBLKMAX];      // after rescan: base | scanned_offset<<16
    __shared__ int ps[256];
    __shared__ int seg[BCAP];
    __shared__ int lcnt[BKT_N];
    __shared__ int lcur[BKT_N];
    int b = blockIdx.x, t = threadIdx.x;
    int n0 = b << BKT_SHIFT;
    int s = boff[b];
    int len = boff[b + 1] - s;
    for (int k = t; k < NBLK; k += 256) cc[k] = cntmatT[(size_t)b * NBLK + k];
    if (t < BKT_N) lcnt[t] = 0;
    __syncthreads();
    int chunk = (NBLK + 255) >> 8;
    int lo = t * chunk; if (lo > NBLK) lo = NBLK;
    int hi = lo + chunk; if (hi > NBLK) hi = NBLK;
    int sm = 0;
    for (int i = lo; i < hi; ++i) sm += (cc[i] >> 16) & 0xFFFF;
    ps[t] = sm;
    __syncthreads();
    for (int d = 1; d < 256; d <<= 1) {
        int v = (t >= d) ? ps[t - d] : 0;
        __syncthreads();
        ps[t] += v;
        __syncthreads();
    }
    int base = (t == 0) ? 0 : ps[t - 1];
    for (int i = lo; i < hi; ++i) {
        int c = (cc[i] >> 16) & 0xFFFF;
        cc[i] = (cc[i] & 0xFFFF) | (base << 16);
        base += c;
    }
    __syncthreads();
    bool fits = (len <= BCAP);
    for (int i = t; i < len; i += 256) {
        int l = 0, h = NBLK;
        while (h - l > 1) { int m = (l + h) >> 1; if ((cc[m] >> 16) <= i) l = m; else h = m; }
        int v = ebuf[l * CHA + (cc[l] & 0xFFFF) + (i - (cc[l] >> 16))];
        if (fits) seg[i] = v;
        atomicAdd(&lcnt[v >> 17], 1);
    }
    __syncthreads();
    if (t == 0) {
        int run = s;
        for (int i = 0; i < BKT_N; ++i) { lcur[i] = run; run += lcnt[i]; }
    }
    __syncthreads();
    if (t < BKT_N) {
        int n = n0 + t;
        if (n < N) { off[n] = lcur[t]; dinv[n] = rsqrtf((float)lcnt[t] + 1.0f); }
    }
    __syncthreads();
    if (fits) {
        for (int i = t; i < len; i += 256) {
            int v = seg[i];
            int pos = atomicAdd(&lcur[v >> 17], 1);
            eby[pos] = v & 0x1FFFF;
        }
    } else {
        for (int i = t; i < len; i += 256) {
            int l = 0, h = NBLK;
            while (h - l > 1) { int m = (l + h) >> 1; if ((cc[m] >> 16) <= i) l = m; else h = m; }
            int v = ebuf[l * CHA + (cc[l] & 0xFFFF) + (i - (cc[l] >> 16))];
            int pos = atomicAdd(&lcur[v >> 17], 1);
            eby[pos] = v & 0x1FFFF;
        }
    }
}

// ---------------- layer-1 GEMM (register-blocked; output pre-scaled by dinv) ------

__global__ void gemm128_32v(const float* __restrict__ x, const float* __restrict__ W,
                            const float* __restrict__ dinv, float* __restrict__ h, int N) {
    __shared__ float Ws[128 * 32];
    int t = threadIdx.x;
    for (int i = t; i < 128 * 32; i += 256) Ws[i] = W[i];
    __syncthreads();
    int cg = (t & 7) * 4;
    int n0 = blockIdx.x * 128 + (t >> 3) * 4;
    if (n0 >= N) return;
    if (n0 + 4 <= N) {
        const float* xr = x + (size_t)n0 * 128;
        float4 a0 = {0,0,0,0}, a1 = a0, a2 = a0, a3 = a0;
#pragma unroll
        for (int k4 = 0; k4 < 32; ++k4) {
            float4 x0 = *(const float4*)(xr + k4 * 4);
            float4 x1 = *(const float4*)(xr + 128 + k4 * 4);
            float4 x2 = *(const float4*)(xr + 256 + k4 * 4);
            float4 x3 = *(const float4*)(xr + 384 + k4 * 4);
            float4 w0 = *(const float4*)&Ws[(4 * k4 + 0) * 32 + cg];
            float4 w1 = *(const float4*)&Ws[(4 * k4 + 1) * 32 + cg];
            float4 w2 = *(const float4*)&Ws[(4 * k4 + 2) * 32 + cg];
            float4 w3 = *(const float4*)&Ws[(4 * k4 + 3) * 32 + cg];
            fma4(a0, x0.x, w0); fma4(a0, x0.y, w1); fma4(a0, x0.z, w2); fma4(a0, x0.w, w3);
            fma4(a1, x1.x, w0); fma4(a1, x1.y, w1); fma4(a1, x1.z, w2); fma4(a1, x1.w, w3);
            fma4(a2, x2.x, w0); fma4(a2, x2.y, w1); fma4(a2, x2.z, w2); fma4(a2, x2.w, w3);
            fma4(a3, x3.x, w0); fma4(a3, x3.y, w1); fma4(a3, x3.z, w2); fma4(a3, x3.w, w3);
        }
        scl4(a0, dinv[n0]); scl4(a1, dinv[n0 + 1]); scl4(a2, dinv[n0 + 2]); scl4(a3, dinv[n0 + 3]);
        *(float4*)&h[(size_t)(n0 + 0) * 32 + cg] = a0;
        *(float4*)&h[(size_t)(n0 + 1) * 32 + cg] = a1;
        *(float4*)&h[(size_t)(n0 + 2) * 32 + cg] = a2;
        *(float4*)&h[(size_t)(n0 + 3) * 32 + cg] = a3;
    } else {
        for (int nn = 0; nn < 4; ++nn) {
            int n = n0 + nn; if (n >= N) break;
            float4 a = {0,0,0,0};
            for (int k = 0; k < 128; ++k)
                fma4(a, x[(size_t)n * 128 + k], *(const float4*)&Ws[k * 32 + cg]);
            scl4(a, dinv[n]);
            *(float4*)&h[(size_t)n * 32 + cg] = a;
        }
    }
}

// ---------------- fused aggregation + next-layer GEMM epilogue ----------------
// h is pre-scaled by dinv: row = tanh(dn * (h'[n] + sum h'[s]) + b)  -> xc slice
// epilogue (W variant):  hnext[n] = (row @ Wn) * dn      (8-lane group shuffle)
// epilogue (v variant):  hv[n]    = (row @ W4) * dn      (8-lane group reduce)

__global__ void agg32f_w(const float* __restrict__ h, const int* __restrict__ off,
                         const int* __restrict__ eby, const float* __restrict__ dinv,
                         const float* __restrict__ b, const float* __restrict__ Wn,
                         float* __restrict__ xc, int colOff,
                         float* __restrict__ hnext, int N) {
    __shared__ float Ws[32 * 32];
    int t = threadIdx.x;
    for (int i = t; i < 1024; i += 256) Ws[i] = Wn[i];
    __syncthreads();
    int idx = blockIdx.x * 256 + t;
    int n = idx >> 3, q = idx & 7;
    if (n >= N) return;
    const float4* h4 = (const float4*)h;
    float dn = dinv[n];
    float4 acc = h4[(size_t)n * 8 + q];
    float4 c1 = {0,0,0,0}, c2 = {0,0,0,0}, c3 = {0,0,0,0};
    int e0 = off[n], e1 = off[n + 1];
    int j = e0;
    for (; j + 3 < e1; j += 4) {
        int s0 = eby[j], s1 = eby[j + 1], s2 = eby[j + 2], s3 = eby[j + 3];
        float4 h0 = h4[(size_t)s0 * 8 + q];
        float4 h1 = h4[(size_t)s1 * 8 + q];
        float4 h2 = h4[(size_t)s2 * 8 + q];
        float4 h3 = h4[(size_t)s3 * 8 + q];
        add4(acc, h0); add4(c1, h1); add4(c2, h2); add4(c3, h3);
    }
    for (; j < e1; ++j) add4(acc, h4[(size_t)eby[j] * 8 + q]);
    add4(c1, c2); add4(acc, c3); add4(acc, c1);
    float4 bb = *(const float4*)&b[q * 4];
    float4 o;
    o.x = tanhf(acc.x * dn + bb.x);
    o.y = tanhf(acc.y * dn + bb.y);
    o.z = tanhf(acc.z * dn + bb.z);
    o.w = tanhf(acc.w * dn + bb.w);
    *(float4*)&xc[(size_t)n * XCS + colOff + q * 4] = o;
    // epilogue: next-layer GEMM on the in-register row (8-lane group)
    int cg = q * 4;
    float4 hn = {0,0,0,0};
#pragma unroll
    for (int kq = 0; kq < 8; ++kq) {
        float4 rk;
        rk.x = __shfl(o.x, kq, 8);
        rk.y = __shfl(o.y, kq, 8);
        rk.z = __shfl(o.z, kq, 8);
        rk.w = __shfl(o.w, kq, 8);
        int k = kq * 4;
        fma4(hn, rk.x, *(const float4*)&Ws[k * 32 + cg]);
        fma4(hn, rk.y, *(const float4*)&Ws[(k + 1) * 32 + cg]);
        fma4(hn, rk.z, *(const float4*)&Ws[(k + 2) * 32 + cg]);
        fma4(hn, rk.w, *(const float4*)&Ws[(k + 3) * 32 + cg]);
    }
    scl4(hn, dn);
    *(float4*)&hnext[(size_t)n * 32 + cg] = hn;
}

__global__ void agg32f_v(const float* __restrict__ h, const int* __restrict__ off,
                         const int* __restrict__ eby, const float* __restrict__ dinv,
                         const float* __restrict__ b, const float* __restrict__ W4,
                         float* __restrict__ xc, int colOff,
                         float* __restrict__ hv, int N) {
    __shared__ float W4s[32];
    int t = threadIdx.x;
    if (t < 32) W4s[t] = W4[t];
    __syncthreads();
    int idx = blockIdx.x * 256 + t;
    int n = idx >> 3, q = idx & 7;
    if (n >= N) return;
    const float4* h4 = (const float4*)h;
    float dn = dinv[n];
    float4 acc = h4[(size_t)n * 8 + q];
    float4 c1 = {0,0,0,0}, c2 = {0,0,0,0}, c3 = {0,0,0,0};
    int e0 = off[n], e1 = off[n + 1];
    int j = e0;
    for (; j + 3 < e1; j += 4) {
        int s0 = eby[j], s1 = eby[j + 1], s2 = eby[j + 2], s3 = eby[j + 3];
        float4 h0 = h4[(size_t)s0 * 8 + q];
        float4 h1 = h4[(size_t)s1 * 8 + q];
        float4 h2 = h4[(size_t)s2 * 8 + q];
        float4 h3 = h4[(size_t)s3 * 8 + q];
        add4(acc, h0); add4(c1, h1); add4(c2, h2); add4(c3, h3);
    }
    for (; j < e1; ++j) add4(acc, h4[(size_t)eby[j] * 8 + q]);
    add4(c1, c2); add4(acc, c3); add4(acc, c1);
    float4 bb = *(const float4*)&b[q * 4];
    float4 o;
    o.x = tanhf(acc.x * dn + bb.x);
    o.y = tanhf(acc.y * dn + bb.y);
    o.z = tanhf(acc.z * dn + bb.z);
    o.w = tanhf(acc.w * dn + bb.w);
    *(float4*)&xc[(size_t)n * XCS + colOff + q * 4] = o;
    // epilogue: hv[n] = (row @ W4) * dn via 8-lane reduce
    int cg = q * 4;
    float p = o.x * W4s[cg] + o.y * W4s[cg + 1] + o.z * W4s[cg + 2] + o.w * W4s[cg + 3];
    p += __shfl_xor(p, 1, 8);
    p += __shfl_xor(p, 2, 8);
    p += __shfl_xor(p, 4, 8);
    if (q == 0) hv[n] = p * dn;
}

__global__ void agg1(const float* __restrict__ hv, const int* __restrict__ off,
                     const int* __restrict__ eby, const float* __restrict__ dinv,
                     const float* __restrict__ b4, float* __restrict__ xc, int N) {
    int n = blockIdx.x * 256 + threadIdx.x;
    if (n >= N) return;
    float dn = dinv[n];
    float acc = hv[n], c1 = 0.f, c2 = 0.f, c3 = 0.f;
    int e0 = off[n], e1 = off[n + 1];
    int j = e0;
    for (; j + 3 < e1; j += 4) {
        acc += hv[eby[j]]; c1 += hv[eby[j + 1]]; c2 += hv[eby[j + 2]]; c3 += hv[eby[j + 3]];
    }
    for (; j < e1; ++j) acc += hv[eby[j]];
    xc[(size_t)n * XCS + 96] = tanhf((acc + c1 + c2 + c3) * dn + b4[0]);
}

// ---------------- fused head ----------------

__global__ void head_kernel(const float* __restrict__ xc,
                            const float* __restrict__ c5w, const float* __restrict__ c5b,
                            const float* __restrict__ c6w, const float* __restrict__ c6b,
                            const float* __restrict__ f1w, const float* __restrict__ f1b,
                            const float* __restrict__ f2w, const float* __restrict__ f2b,
                            float* __restrict__ out) {
    __shared__ float v[NPG];
    __shared__ int   ord[KK];
    __shared__ float topk[KK * FC];
    __shared__ float o5[16 * 30];
    __shared__ float p5[16 * 15];
    __shared__ float z[352];
    __shared__ float h1[128];
    __shared__ float lg[NC];
    __shared__ float lse;

    int g = blockIdx.x;
    int t = threadIdx.x;
    const float* xg = xc + (size_t)g * NPG * XCS;

    if (t < NPG) v[t] = xg[t * XCS + 96];
    __syncthreads();
    if (t < NPG) {
        float vi = v[t];
        int r = 0;
        for (int j = 0; j < NPG; ++j) {
            float vj = v[j];
            r += (vj > vi) || (vj == vi && j < t);  // stable descending rank
        }
        if (r < KK) ord[r] = t;
    }
    __syncthreads();
    for (int i = t; i < KK * FC; i += 128) {
        int r = i / FC, f = i - r * FC;
        topk[i] = xg[ord[r] * XCS + f];
    }
    __syncthreads();
    for (int i = t; i < 16 * 30; i += 128) {
        int ch = i / 30, tt = i - ch * 30;
        float a = c5b[ch];
        const float* w = c5w + ch * FC;
        const float* xx = topk + tt * FC;
        for (int f = 0; f < FC; ++f) a += xx[f] * w[f];
        o5[ch * 30 + tt] = fmaxf(a, 0.f);
    }
    __syncthreads();
    for (int i = t; i < 16 * 15; i += 128) {
        int ch = i / 15, tt = i - ch * 15;
        p5[i] = fmaxf(o5[ch * 30 + 2 * tt], o5[ch * 30 + 2 * tt + 1]);
    }
    __syncthreads();
    for (int i = t; i < 32 * 11; i += 128) {
        int oc = i / 11, tt = i - oc * 11;
        float a = c6b[oc];
#pragma unroll
        for (int ic = 0; ic < 16; ++ic) {
#pragma unroll
            for (int k = 0; k < 5; ++k)
                a += p5[ic * 15 + tt + k] * c6w[oc * 80 + ic * 5 + k];
        }
        z[oc * 11 + tt] = fmaxf(a, 0.f);
    }
    __syncthreads();
    {
        float a = f1b[t];
        for (int i = 0; i < 352; ++i) a += z[i] * f1w[i * 128 + t];
        h1[t] = fmaxf(a, 0.f);
    }
    __syncthreads();
    if (t < NC) {
        float a = f2b[t];
#pragma unroll
        for (int j = 0; j < 128; ++j) a += h1[j] * f2w[j * NC + t];
        lg[t] = a;
    }
    __syncthreads();
    if (t == 0) {
        float m = lg[0];
        for (int c = 1; c < NC; ++c) m = fmaxf(m, lg[c]);
        float s = 0.f;
        for (int c = 0; c < NC; ++c) s += expf(lg[c] - m);
        lse = m + logf(s);
    }
    __syncthreads();
    if (t < NC) out[(size_t)g * NC + t] = lg[t] - lse;
}

// ---------------- launch ----------------

static inline size_t align_up(size_t x, size_t a) { return (x + a - 1) & ~(a - 1); }

extern "C" void kernel_launch(void* const* d_in, const int* in_sizes, int n_in,
                              void* d_out, int out_size, void* d_ws, size_t ws_size,
                              hipStream_t stream) {
    const float* x   = (const float*)d_in[0];
    const int*   ei  = (const int*)d_in[1];
    const float* W1  = (const float*)d_in[3];
    const float* b1  = (const float*)d_in[4];
    const float* W2  = (const float*)d_in[5];
    const float* b2  = (const float*)d_in[6];
    const float* W3  = (const float*)d_in[7];
    const float* b3  = (const float*)d_in[8];
    const float* W4  = (const float*)d_in[9];
    const float* b4  = (const float*)d_in[10];
    const float* c5w = (const float*)d_in[11];
    const float* c5b = (const float*)d_in[12];
    const float* c6w = (const float*)d_in[13];
    const float* c6b = (const float*)d_in[14];
    const float* f1w = (const float*)d_in[15];
    const float* f1b = (const float*)d_in[16];
    const float* f2w = (const float*)d_in[17];
    const float* f2b = (const float*)d_in[18];
    float* out = (float*)d_out;

    const int N = in_sizes[0] / FIN;
    const int E = in_sizes[1] / 2;
    const int G = N / NPG;
    const int NB = (N + BKT_N - 1) >> BKT_SHIFT;  // buckets of 64 nodes
    const int NBLK = (E + CHA - 1) / CHA;         // sort blocks
    const int* src = ei;
    const int* dst = ei + E;

    // workspace plan (with lifetime unions):
    //  [colsum][boff][dinv][off][hv][hB][ ebuf | hA ][ eby | cntmat ][ xcb | cntmatT ]
    //  cntmat:  written by sortA, read by transp, dead before bucketB writes eby
    //  cntmatT: written by transp, read by colsum_k/bucketB, dead before agg writes xcb
    //  ebuf:    written by sortA, read by bucketB, dead before gemm writes hA
    char* ws = (char*)d_ws;
    size_t o = 0;
    int*   colsum = (int*)(ws + o); o = align_up(o + (size_t)NB * 4, 256);
    int*   boff   = (int*)(ws + o); o = align_up(o + (size_t)(NB + 1) * 4, 256);
    float* dinv   = (float*)(ws + o); o = align_up(o + (size_t)N * 4, 256);
    int*   off    = (int*)(ws + o); o = align_up(o + (size_t)(N + 1) * 4, 256);
    float* hv     = (float*)(ws + o); o = align_up(o + (size_t)N * 4, 256);
    float* hB     = (float*)(ws + o); o = align_up(o + (size_t)N * 32 * 4, 256);
    size_t big = (size_t)(E > N * 32 ? E : N * 32);
    int*   ebuf   = (int*)(ws + o); float* hA = (float*)(ws + o);
    o = align_up(o + big * 4, 256);
    size_t big2 = (size_t)E * 4 > (size_t)NBLK * NB * 4 ? (size_t)E * 4 : (size_t)NBLK * NB * 4;
    int*   eby    = (int*)(ws + o); int* cntmat = (int*)(ws + o);
    o = align_up(o + big2, 256);
    size_t big3 = (size_t)N * XCS * 4 > (size_t)NBLK * NB * 4 ? (size_t)N * XCS * 4 : (size_t)NBLK * NB * 4;
    float* xcb    = (float*)(ws + o); int* cntmatT = (int*)(ws + o);
    o = align_up(o + big3, 256);
    (void)ws_size;

    int gbN  = (N + 255) / 256;
    int gbN8 = ((size_t)N * 8 + 255) / 256;
    int gbN128 = (N + 127) / 128;

    sortA<<<NBLK, 256, 0, stream>>>(src, dst, ebuf, cntmat, E, NB);
    dim3 tg((NB + TT - 1) / TT, (NBLK + TT - 1) / TT);
    transp<<<tg, 256, 0, stream>>>(cntmat, cntmatT, NBLK, NB);
    colsum_k<<<NB, 256, 0, stream>>>(cntmatT, colsum, NBLK);
    scan_nb<<<1, 256, 0, stream>>>(colsum, boff, off, NB, N, E);
    bucketB<<<NB, 256, 0, stream>>>(ebuf, cntmatT, boff, eby, off, dinv, N, NB, NBLK);

    // layer 1 GEMM: x @ W1 -> hA (pre-scaled)
    gemm128_32v<<<gbN128, 256, 0, stream>>>(x, W1, dinv, hA, N);
    // layer 1 agg + layer 2 GEMM epilogue: hA -> xc[:,0:32], hB
    agg32f_w<<<gbN8, 256, 0, stream>>>(hA, off, eby, dinv, b1, W2, xcb, 0, hB, N);
    // layer 2 agg + layer 3 GEMM epilogue: hB -> xc[:,32:64], hA
    agg32f_w<<<gbN8, 256, 0, stream>>>(hB, off, eby, dinv, b2, W3, xcb, 32, hA, N);
    // layer 3 agg + layer 4 GEMM epilogue: hA -> xc[:,64:96], hv
    agg32f_v<<<gbN8, 256, 0, stream>>>(hA, off, eby, dinv, b3, W4, xcb, 64, hv, N);
    // layer 4 agg: hv -> xc[:,96]
    agg1<<<gbN, 256, 0, stream>>>(hv, off, eby, dinv, b4, xcb, N);

    // head
    head_kernel<<<G, 128, 0, stream>>>(xcb, c5w, c5b, c6w, c6b, f1w, f1b, f2w, f2b, out);
}